// Round 1
// baseline (406.535 us; speedup 1.0000x reference)
//
#include <hip/hip_runtime.h>

// HMM scaled forward, register-resident MFMA recurrence — FUSED decode.
//   BATCH=128, T=8192, N_STATES=128, EMIT=64
// v2 change: the 268 MB one-hot read no longer runs as a serialized decode
// kernel. Each scan block streams its own chunk's one-hot rows (4 KB/step)
// through a depth-2 register prefetch pipeline, decoding them to obs bytes
// via a 16-byte LDS ping-pong bounce — the HBM stream hides under the MFMA
// recurrence. obsG workspace and the decode kernel are gone.
// __launch_bounds__(64,2) pins <=256 VGPR (2 waves/SIMD); s_setprio wraps
// the MFMA cluster (independent 1-wave blocks, m191-style).

#define BATCH 128
#define TLEN 8192
#define NS 128
#define EMIT 64
#define NCHUNK 256
#define CLEN (TLEN / NCHUNK)   // 32
#define WARM 8
#define BG 8                   // batch groups of 16
#define BSTR 132               // B-table row stride (bf16 elems)
#define LN64 4.158883083359672f

typedef __attribute__((ext_vector_type(8))) short short8;
typedef __attribute__((ext_vector_type(4))) float floatx4;
typedef __attribute__((ext_vector_type(4))) unsigned int uintx4;

__device__ __forceinline__ unsigned f2bf(float f) {
    return (__float_as_uint(f) + 0x8000u) >> 16;   // round-half-up to bf16
}

// ---- one-hot prefetch/decode ------------------------------------------
// A step needs 16 rows (one per batch in the group) x 256 B. One
// global_load_dwordx4 instruction covers 4 rows: lane l reads float4
// (l&15) of row 4*g + (l>>4). Exactly one of the 16 lanes covering a row
// sees the 1.0; it writes the emission byte into obsb[par][row]; then
// every lane reads back obsb[par][lane&15] (same-dword broadcast, free).

#define ISSUE(P0, P1, P2, P3, s) do {                                     \
    int _o = (s) * 16;                                                    \
    P0 = __builtin_nontemporal_load(&X[b0 + _o]);                         \
    P1 = __builtin_nontemporal_load(&X[b1 + _o]);                         \
    P2 = __builtin_nontemporal_load(&X[b2 + _o]);                         \
    P3 = __builtin_nontemporal_load(&X[b3 + _o]);                         \
} while (0)

#define DEC1(V, g, par) do {                                              \
    float _s = V.x + V.y + V.z + V.w;                                     \
    if (_s > 0.5f) {                                                      \
        int _e = (dcol << 2) +                                            \
                 ((V.y > 0.5f) ? 1 : (V.z > 0.5f) ? 2 :                   \
                  (V.w > 0.5f) ? 3 : 0);                                  \
        obsb[par][4 * (g) + drow] = (unsigned char)_e;                    \
    }                                                                     \
} while (0)

#define DECODE(P0, P1, P2, P3, par, dst) do {                             \
    DEC1(P0, 0, par); DEC1(P1, 1, par);                                   \
    DEC1(P2, 2, par); DEC1(P3, 3, par);                                   \
    dst = obsb[par][n];                                                   \
} while (0)

// One recurrence step IT: reissue the dead prefetch regs RA* for step
// IT+2 (clamped), decode RB* (step IT+1's rows) to _onx, then the
// unchanged MFMA -> emission-mul -> reductions -> pack math using o_cur.
#define STEP(IT, RA0, RA1, RA2, RA3, RB0, RB1, RB2, RB3, PAR) do {        \
    int _nx = (IT) + 2; if (_nx > steps - 1) _nx = steps - 1;             \
    ISSUE(RA0, RA1, RA2, RA3, _nx);                                       \
    int _onx = o_cur;                                                     \
    if ((IT) + 1 < steps) DECODE(RB0, RB1, RB2, RB3, PAR, _onx);          \
    floatx4 acc[8];                                                       \
    if (first && (IT) == 0) {                                             \
        _Pragma("unroll")                                                 \
        for (int mt = 0; mt < 8; ++mt)                                    \
            acc[mt] = *(const floatx4*)(Ivec + 16 * mt + 4 * q);          \
    } else {                                                              \
        short8 bf[4];                                                     \
        _Pragma("unroll")                                                 \
        for (int kf = 0; kf < 4; ++kf) {                                  \
            uintx4 _u4 = {pk[4 * kf], pk[4 * kf + 1],                     \
                          pk[4 * kf + 2], pk[4 * kf + 3]};                \
            bf[kf] = __builtin_bit_cast(short8, _u4);                     \
        }                                                                 \
        __builtin_amdgcn_s_setprio(1);                                    \
        _Pragma("unroll")                                                 \
        for (int mt = 0; mt < 8; ++mt) {                                  \
            floatx4 _a = {0.f, 0.f, 0.f, 0.f};                            \
            _Pragma("unroll")                                             \
            for (int kf = 0; kf < 4; ++kf)                                \
                _a = __builtin_amdgcn_mfma_f32_16x16x32_bf16(             \
                        af[mt][kf], bf[kf], _a, 0, 0, 0);                 \
            acc[mt] = _a;                                                 \
        }                                                                 \
        __builtin_amdgcn_s_setprio(0);                                    \
    }                                                                     \
    int _eb = o_cur * BSTR;                                               \
    _Pragma("unroll")                                                     \
    for (int mt = 0; mt < 8; ++mt) {                                      \
        const unsigned* _ep = (const unsigned*)(Bl + _eb + 16*mt + 4*q);  \
        unsigned _d0 = _ep[0], _d1 = _ep[1];                              \
        acc[mt].x *= __uint_as_float(_d0 << 16);                          \
        acc[mt].y *= __uint_as_float(_d0 & 0xFFFF0000u);                  \
        acc[mt].z *= __uint_as_float(_d1 << 16);                          \
        acc[mt].w *= __uint_as_float(_d1 & 0xFFFF0000u);                  \
    }                                                                     \
    bool _red = ((IT) == steps - 1) || (!first && (IT) == WARM - 1) ||    \
                (lastc && (IT) == steps - 2);                             \
    if (_red) {                                                           \
        float _zz = 0.f;                                                  \
        _Pragma("unroll")                                                 \
        for (int mt = 0; mt < 8; ++mt)                                    \
            _zz += (acc[mt].x + acc[mt].y) + (acc[mt].z + acc[mt].w);     \
        _zz += __shfl_xor(_zz, 16, 64);                                   \
        _zz += __shfl_xor(_zz, 32, 64);                                   \
        if ((IT) == steps - 1) s_end = _zz;                               \
        else if (lastc && (IT) == steps - 2) s_penult = _zz;              \
        else s_pre = _zz;                                                 \
    }                                                                     \
    if (lastc && (IT) == steps - 1) {                                     \
        float _inv = 1.0f / (64.0f * s_penult);                           \
        _Pragma("unroll")                                                 \
        for (int mt = 0; mt < 8; ++mt) {                                  \
            floatx4 _o4;                                                  \
            _o4.x = acc[mt].x * _inv; _o4.y = acc[mt].y * _inv;           \
            _o4.z = acc[mt].z * _inv; _o4.w = acc[mt].w * _inv;           \
            *(floatx4*)(out_alpha + (bg*16 + n)*NS + 16*mt + 4*q) = _o4;  \
        }                                                                 \
    }                                                                     \
    _Pragma("unroll")                                                     \
    for (int mt = 0; mt < 8; ++mt) {                                      \
        unsigned _u0 = __float_as_uint(acc[mt].x) + 0x8000u;              \
        unsigned _u1 = __float_as_uint(acc[mt].y) + 0x8000u;              \
        unsigned _u2 = __float_as_uint(acc[mt].z) + 0x8000u;              \
        unsigned _u3 = __float_as_uint(acc[mt].w) + 0x8000u;              \
        pk[2*mt]     = __builtin_amdgcn_perm(_u1, _u0, 0x07060302u);      \
        pk[2*mt + 1] = __builtin_amdgcn_perm(_u3, _u2, 0x07060302u);      \
    }                                                                     \
    o_cur = _onx;                                                         \
} while (0)

__global__ __launch_bounds__(64, 2) void hmm_scan(
        const float* __restrict__ Amat,
        const float* __restrict__ Bmat,
        const float* __restrict__ Ivec,
        const floatx4* __restrict__ X,    // one-hot input as float4
        float* __restrict__ out_alpha,    // [BATCH][NS]
        float* __restrict__ out_ll)       // [BATCH]
{
    __shared__ unsigned short Bl[EMIT * BSTR];    // 16896 B: bf16(64*B)
    __shared__ unsigned char obsb[2][16];         // obs byte ping-pong

    const int lane = threadIdx.x;
    const int n = lane & 15;              // batch within group (D col)
    const int q = lane >> 4;              // quad
    const int bg = blockIdx.x >> 8;       // / NCHUNK
    const int c = blockIdx.x & (NCHUNK - 1);
    const bool first = (c == 0);
    const bool lastc = (c == NCHUNK - 1);
    const int steps = first ? CLEN : (CLEN + WARM);   // 32 or 40, even
    const int t0 = first ? 0 : c * CLEN - WARM;

    // stage B scaled by 64 (exact pow2) as bf16, padded stride
    for (int i = lane; i < EMIT * NS; i += 64) {
        int e = i >> 7, col = i & (NS - 1);
        Bl[e * BSTR + col] = (unsigned short)f2bf(64.0f * Bmat[i]);
    }

    // A fragments with permuted K-order so packed D == next B-frag.
    short8 af[8][4];
    #pragma unroll
    for (int mt = 0; mt < 8; ++mt)
        #pragma unroll
        for (int kf = 0; kf < 4; ++kf) {
            short8 v;
            #pragma unroll
            for (int j = 0; j < 8; ++j) {
                int u = 32 * kf + 8 * q + j;
                int sk = 32 * (u >> 5) + 16 * ((u >> 2) & 1)
                       + 4 * ((u >> 3) & 3) + (u & 3);
                v[j] = (short)f2bf(Amat[sk * NS + 16 * mt + n]);
            }
            af[mt][kf] = v;
        }

    // prefetch lane roles + per-lane float4 base offsets (fit in int)
    const int drow = lane >> 4;
    const int dcol = lane & 15;
    const int b0 = ((bg * 16 +  0 + drow) * TLEN + t0) * 16 + dcol;
    const int b1 = ((bg * 16 +  4 + drow) * TLEN + t0) * 16 + dcol;
    const int b2 = ((bg * 16 +  8 + drow) * TLEN + t0) * 16 + dcol;
    const int b3 = ((bg * 16 + 12 + drow) * TLEN + t0) * 16 + dcol;

    // prologue: load steps 0 and 1, decode step 0 -> o_cur
    floatx4 A0, A1, A2, A3, B0, B1, B2, B3;
    ISSUE(A0, A1, A2, A3, 0);
    ISSUE(B0, B1, B2, B3, 1);
    int o_cur;
    { int _tmp; DECODE(A0, A1, A2, A3, 0, _tmp); o_cur = _tmp; }

    // loop-carried packed alpha (bf16 pairs); init uniform for warmup
    unsigned pk[16];
    #pragma unroll
    for (int i = 0; i < 16; ++i) pk[i] = 0x3C003C00u;   // bf16(1/128) x2

    float s_pre = 1.0f, s_penult = 1.0f, s_end = 1.0f;

    __syncthreads();   // Bl ready

    for (int it = 0; it < steps; it += 2) {
        STEP(it,     A0, A1, A2, A3, B0, B1, B2, B3, 1);
        STEP(it + 1, B0, B1, B2, B3, A0, A1, A2, A3, 0);
    }

    // chunk ll partial: telescoped  log(S_end) - log(S_pre) - CLEN*ln(64)
    if (q == 0) {
        float ll = __logf(s_end) - __logf(s_pre) - (float)CLEN * LN64;
        atomicAdd(&out_ll[bg * 16 + n], ll);
    }
}

extern "C" void kernel_launch(void* const* d_in, const int* in_sizes, int n_in,
                              void* d_out, int out_size, void* d_ws, size_t ws_size,
                              hipStream_t stream) {
    const float* x = (const float*)d_in[0];   // [B, T, EMIT] one-hot fp32
    const float* I = (const float*)d_in[1];   // [NS]
    const float* A = (const float*)d_in[2];   // [NS, NS]
    const float* B = (const float*)d_in[3];   // [EMIT, NS]
    float* out = (float*)d_out;               // alpha_f [B*NS] ++ loglik [B]

    // zero the loglik accumulators (atomicAdd target)
    hipMemsetAsync(out + BATCH * NS, 0, BATCH * sizeof(float), stream);

    hmm_scan<<<BG * NCHUNK, 64, 0, stream>>>(
        A, B, I, (const floatx4*)x, out, out + BATCH * NS);
}

// Round 2
// 377.338 us; speedup vs baseline: 1.0774x; 1.0774x over previous
//
#include <hip/hip_runtime.h>

// HMM scaled forward, register-resident MFMA recurrence.
//   BATCH=128, T=8192, N_STATES=128, EMIT=64
// v3: split structure (decode kernel at HBM ceiling + 1-wave scan blocks),
// with the scan's per-block table-build preamble eliminated: the permuted
// bf16 A-fragment table (32 KB, block-invariant) and the 64x-scaled bf16
// B table (16 KB) are precomputed once by decode block 0 into workspace.
// Scan preamble drops from ~384 scalar L2 loads + f2bf converts per lane
// to 48 coalesced b128 loads. Main loop unchanged: 32x mfma_16x16x32_bf16
// -> emission mul from LDS -> bf16 pack that IS the next B-fragment.

#define BATCH 128
#define TLEN 8192
#define NS 128
#define EMIT 64
#define NCHUNK 256
#define CLEN (TLEN / NCHUNK)   // 32
#define WARM 8
#define BG 8                   // batch groups of 16
#define BSTR 132               // B-table LDS row stride (bf16 elems), 2-bank skew
#define LN64 4.158883083359672f

typedef __attribute__((ext_vector_type(8))) short short8;
typedef __attribute__((ext_vector_type(4))) float floatx4;
typedef __attribute__((ext_vector_type(4))) unsigned int uintx4;

__device__ __forceinline__ unsigned f2bf(float f) {
    return (__float_as_uint(f) + 0x8000u) >> 16;   // round-half-up to bf16
}

// decode 256 MiB one-hot -> obsG[bg][n][t] bytes (1 MiB); zero out_ll;
// block 0 additionally precomputes the scan's bf16 tables into workspace:
//   AF  [i=mt*4+kf][lane][j]  16384 bf16 (32 KB) — A-fragments, permuted K
//   Bpre[e][col]               8192 bf16 (16 KB) — 64*B, row-major
__global__ __launch_bounds__(256) void decode_onehot(
        const floatx4* __restrict__ x, unsigned char* __restrict__ obsG,
        float* __restrict__ out_ll,
        const float* __restrict__ Amat, const float* __restrict__ Bmat,
        unsigned short* __restrict__ AF, unsigned short* __restrict__ Bpre) {
    if (blockIdx.x == 0) {
        if (threadIdx.x < BATCH) out_ll[threadIdx.x] = 0.f;
        // A-fragment table: position u = 32kf + 8q + j maps to state
        // sk = 32(u>>5) + 16((u>>2)&1) + 4((u>>3)&3) + (u&3), so that the
        // packed MFMA D output is directly the next step's B-fragment.
        #pragma unroll 4
        for (int k = 0; k < 64; ++k) {
            int idx = threadIdx.x + 256 * k;      // ((i*64)+l)*8 + j
            int j = idx & 7, l = (idx >> 3) & 63, i = idx >> 9;
            int mt = i >> 2, kf = i & 3, q = l >> 4, n = l & 15;
            int u = 32 * kf + 8 * q + j;
            int sk = 32 * (u >> 5) + 16 * ((u >> 2) & 1)
                   + 4 * ((u >> 3) & 3) + (u & 3);
            AF[idx] = (unsigned short)f2bf(Amat[sk * NS + 16 * mt + n]);
        }
        #pragma unroll 4
        for (int k = 0; k < 32; ++k) {
            int idx = threadIdx.x + 256 * k;
            Bpre[idx] = (unsigned short)f2bf(64.0f * Bmat[idx]);
        }
    }
    int base = blockIdx.x * 512 + threadIdx.x;
    #pragma unroll
    for (int h = 0; h < 2; ++h) {
        int i = base + h * 256;                    // BATCH*TLEN*16 float4s
        floatx4 v = __builtin_nontemporal_load(&x[i]);
        float s = v.x + v.y + v.z + v.w;
        if (s > 0.5f) {
            int e = (v.y > 0.5f) ? 1 : (v.z > 0.5f) ? 2 : (v.w > 0.5f) ? 3 : 0;
            int elem = (i << 2) + e;
            int row = elem >> 6;                   // b*TLEN + t
            int col = elem & 63;                   // emission symbol
            int b = row >> 13;
            int t = row & (TLEN - 1);
            obsG[(b >> 4) * (16 * TLEN) + (b & 15) * TLEN + t] = (unsigned char)col;
        }
    }
}

__global__ __launch_bounds__(64) void hmm_scan(
        const unsigned short* __restrict__ AF,
        const unsigned short* __restrict__ Bpre,
        const float* __restrict__ Ivec,
        const unsigned char* __restrict__ obsG,
        float* __restrict__ out_alpha,    // [BATCH][NS]
        float* __restrict__ out_ll)       // [BATCH]
{
    __shared__ unsigned short Bl[EMIT * BSTR];    // 16896 B: bf16(64*B)

    const int lane = threadIdx.x;
    const int n = lane & 15;              // batch within group (D col)
    const int q = lane >> 4;              // quad
    const int bg = blockIdx.x >> 8;       // / NCHUNK
    const int c = blockIdx.x & (NCHUNK - 1);
    const bool first = (c == 0);
    const bool lastc = (c == NCHUNK - 1);
    const int steps = first ? CLEN : (CLEN + WARM);
    const int t0 = first ? 0 : c * CLEN - WARM;

    // stage B table: 16 coalesced b128 loads -> 32 aligned b64 LDS writes
    #pragma unroll
    for (int i = 0; i < 16; ++i) {
        int eb = i * 512 + lane * 8;              // elem index in Bpre
        int e = eb >> 7, cc = eb & 127;
        short8 v = *(const short8*)(Bpre + eb);
        uintx4 u = __builtin_bit_cast(uintx4, v);
        uint2 lo, hi;
        lo.x = u.x; lo.y = u.y; hi.x = u.z; hi.y = u.w;
        *(uint2*)(Bl + e * BSTR + cc) = lo;       // (e*264 + cc*2) is 8B-aligned
        *(uint2*)(Bl + e * BSTR + cc + 4) = hi;
    }

    // A fragments: 32 coalesced b128 loads (AF laid out [frag][lane])
    short8 af[8][4];
    {
        const short8* AFv = (const short8*)AF;
        #pragma unroll
        for (int i = 0; i < 32; ++i)
            af[i >> 2][i & 3] = AFv[i * 64 + lane];
    }

    // this lane's obs bytes -> 10 dwords in registers (obsG row is batch n)
    const unsigned char* orow = obsG + bg * (16 * TLEN) + n * TLEN;
    unsigned ow[10];
    if (first) {                          // t0==0, 32 bytes, 16B aligned
        uintx4 a = *(const uintx4*)(orow);
        uintx4 b = *(const uintx4*)(orow + 16);
        ow[0] = a.x; ow[1] = a.y; ow[2] = a.z; ow[3] = a.w;
        ow[4] = b.x; ow[5] = b.y; ow[6] = b.z; ow[7] = b.w;
        ow[8] = 0; ow[9] = 0;
    } else {                              // t0 = 32c-8: 8B then 16B aligned
        uint2 a = *(const uint2*)(orow + t0);
        uintx4 b = *(const uintx4*)(orow + t0 + 8);
        uintx4 d = *(const uintx4*)(orow + t0 + 24);
        ow[0] = a.x; ow[1] = a.y;
        ow[2] = b.x; ow[3] = b.y; ow[4] = b.z; ow[5] = b.w;
        ow[6] = d.x; ow[7] = d.y; ow[8] = d.z; ow[9] = d.w;
    }
    __syncthreads();   // Bl ready

    // loop-carried packed alpha (bf16 pairs); init uniform for warmup
    unsigned pk[16];
    #pragma unroll
    for (int i = 0; i < 16; ++i) pk[i] = 0x3C003C00u;   // bf16(1/128) x2

    float s_pre = 1.0f, s_penult = 1.0f, s_end = 1.0f;

    for (int it = 0; it < steps; ++it) {
        floatx4 acc[8];
        if (first && it == 0) {
            // t==0: R := I (exact init), alpha0 = 64B[o] * I
            #pragma unroll
            for (int mt = 0; mt < 8; ++mt)
                acc[mt] = *(const floatx4*)(Ivec + 16 * mt + 4 * q);
        } else {
            short8 bf[4];
            #pragma unroll
            for (int kf = 0; kf < 4; ++kf) {
                uintx4 u4 = {pk[4 * kf], pk[4 * kf + 1], pk[4 * kf + 2], pk[4 * kf + 3]};
                bf[kf] = __builtin_bit_cast(short8, u4);
            }
            __builtin_amdgcn_s_setprio(1);
            #pragma unroll
            for (int mt = 0; mt < 8; ++mt) {
                floatx4 a = {0.f, 0.f, 0.f, 0.f};
                #pragma unroll
                for (int kf = 0; kf < 4; ++kf)
                    a = __builtin_amdgcn_mfma_f32_16x16x32_bf16(af[mt][kf], bf[kf], a, 0, 0, 0);
                acc[mt] = a;
            }
            __builtin_amdgcn_s_setprio(0);
        }

        // emission multiply (table holds 64*B)
        int o = (ow[it >> 2] >> ((it & 3) * 8)) & 0xFF;
        int eb = o * BSTR;
        #pragma unroll
        for (int mt = 0; mt < 8; ++mt) {
            const unsigned* ep = (const unsigned*)(Bl + eb + 16 * mt + 4 * q);
            unsigned d0 = ep[0], d1 = ep[1];
            acc[mt].x *= __uint_as_float(d0 << 16);
            acc[mt].y *= __uint_as_float(d0 & 0xFFFF0000u);
            acc[mt].z *= __uint_as_float(d1 << 16);
            acc[mt].w *= __uint_as_float(d1 & 0xFFFF0000u);
        }

        // rare per-chunk reductions (wave-uniform branch)
        bool need_red = (it == steps - 1) || (!first && it == WARM - 1) ||
                        (lastc && it == steps - 2);
        if (need_red) {
            float zz = 0.f;
            #pragma unroll
            for (int mt = 0; mt < 8; ++mt)
                zz += (acc[mt].x + acc[mt].y) + (acc[mt].z + acc[mt].w);
            zz += __shfl_xor(zz, 16, 64);
            zz += __shfl_xor(zz, 32, 64);      // S-bar per batch, all q-lanes
            if (it == steps - 1) s_end = zz;
            else if (lastc && it == steps - 2) s_penult = zz;
            else s_pre = zz;
        }

        if (lastc && it == steps - 1) {
            // alpha_f = alpha-bar_{T-1} / (64 * S-bar_{T-2})
            float inv = 1.0f / (64.0f * s_penult);
            #pragma unroll
            for (int mt = 0; mt < 8; ++mt) {
                floatx4 o4;
                o4.x = acc[mt].x * inv; o4.y = acc[mt].y * inv;
                o4.z = acc[mt].z * inv; o4.w = acc[mt].w * inv;
                *(floatx4*)(out_alpha + (bg * 16 + n) * NS + 16 * mt + 4 * q) = o4;
            }
        }

        // pack to bf16 pairs: directly forms next step's B-fragments
        #pragma unroll
        for (int mt = 0; mt < 8; ++mt) {
            unsigned u0 = __float_as_uint(acc[mt].x) + 0x8000u;
            unsigned u1 = __float_as_uint(acc[mt].y) + 0x8000u;
            unsigned u2 = __float_as_uint(acc[mt].z) + 0x8000u;
            unsigned u3 = __float_as_uint(acc[mt].w) + 0x8000u;
            pk[2 * mt]     = __builtin_amdgcn_perm(u1, u0, 0x07060302u);
            pk[2 * mt + 1] = __builtin_amdgcn_perm(u3, u2, 0x07060302u);
        }
    }

    // chunk ll partial: telescoped  log(S_end) - log(S_pre) - CLEN*ln(64)
    if (q == 0) {
        float ll = __logf(s_end) - __logf(s_pre) - (float)CLEN * LN64;
        atomicAdd(&out_ll[bg * 16 + n], ll);
    }
}

extern "C" void kernel_launch(void* const* d_in, const int* in_sizes, int n_in,
                              void* d_out, int out_size, void* d_ws, size_t ws_size,
                              hipStream_t stream) {
    const float* x = (const float*)d_in[0];   // [B, T, EMIT] one-hot fp32
    const float* I = (const float*)d_in[1];   // [NS]
    const float* A = (const float*)d_in[2];   // [NS, NS]
    const float* B = (const float*)d_in[3];   // [EMIT, NS]
    float* out = (float*)d_out;               // alpha_f [B*NS] ++ loglik [B]

    unsigned char* obsG = (unsigned char*)d_ws;             // 1 MiB
    unsigned short* AF = (unsigned short*)((char*)d_ws + (1 << 20));   // 32 KB
    unsigned short* Bpre = AF + 32 * 64 * 8;                           // 16 KB

    decode_onehot<<<(BATCH * TLEN * 16) / 512, 256, 0, stream>>>(
        (const floatx4*)x, obsG, out + BATCH * NS, A, B, AF, Bpre);
    hmm_scan<<<BG * NCHUNK, 64, 0, stream>>>(
        AF, Bpre, I, obsG, out, out + BATCH * NS);
}